// Round 5
// baseline (241.897 us; speedup 1.0000x reference)
//
#include <hip/hip_runtime.h>
#include <hip/hip_bf16.h>

#define NLB 4096
#define NULB 6144
#define NROWS 16384   // 4096 + 2*6144
#define DD 128
#define NC 10
#define VW 12                // P12 row width: 10 numerators + denom + pad
#define SEG 16
#define JSEG (NROWS / SEG)   // 1024
#define BI 256               // i-rows per block (4 waves x 64)
#define BJ 128               // j-rows per LDS tile

typedef __bf16 bf16_t;
typedef bf16_t bf16x8 __attribute__((ext_vector_type(8)));
typedef float f32x4 __attribute__((ext_vector_type(4)));
typedef unsigned int u32;

// ================= fused prep =================
// blocks 0..1023   : L2-normalize 16 rows each of [lb;anchor;pos] -> bf16 F
// blocks 1024..1087: build V fragments (interleaved hi/lo bf16) + class counts
// VF layout: group g (16 j-rows), lane l=(q=l>>4, n=l&15), 16B chunk:
//   bytes 0..7 : hi bf16 of V[g*16+q*4+d][n], d=0..3
//   bytes 8..15: lo bf16 (v - hi) of same  -> B-operand frag k=q*8+{0..7}
__global__ void kprep2(const float* __restrict__ lb, const float* __restrict__ an,
                       const float* __restrict__ po, const float* __restrict__ onehot,
                       const float* __restrict__ l1, const float* __restrict__ l2,
                       bf16_t* __restrict__ F, bf16_t* __restrict__ VF,
                       float* __restrict__ cls) {
  __shared__ float Vtmp[256 * 16];
  __shared__ float lcnt[NC];
  int b = blockIdx.x;
  int t = threadIdx.x;

  if (b < 1024) {
    // ---- normalize: 16 rows/block, 16 lanes/row, 8 floats/lane ----
    int row = b * 16 + (t >> 4);
    int l16 = t & 15;
    const float* src;
    if (row < NLB) src = lb + (size_t)row * DD;
    else if (row < NLB + NULB) src = an + (size_t)(row - NLB) * DD;
    else src = po + (size_t)(row - NLB - NULB) * DD;
    float4 v0 = ((const float4*)src)[l16 * 2];
    float4 v1 = ((const float4*)src)[l16 * 2 + 1];
    float ss = v0.x*v0.x + v0.y*v0.y + v0.z*v0.z + v0.w*v0.w
             + v1.x*v1.x + v1.y*v1.y + v1.z*v1.z + v1.w*v1.w;
#pragma unroll
    for (int off = 8; off >= 1; off >>= 1) ss += __shfl_xor(ss, off);
    float inv = 1.0f / fmaxf(sqrtf(ss), 1e-12f);
    union { bf16_t h[8]; uint4 u; } pk;
    pk.h[0] = (bf16_t)(v0.x*inv); pk.h[1] = (bf16_t)(v0.y*inv);
    pk.h[2] = (bf16_t)(v0.z*inv); pk.h[3] = (bf16_t)(v0.w*inv);
    pk.h[4] = (bf16_t)(v1.x*inv); pk.h[5] = (bf16_t)(v1.y*inv);
    pk.h[6] = (bf16_t)(v1.z*inv); pk.h[7] = (bf16_t)(v1.w*inv);
    *(uint4*)(F + (size_t)row * DD + l16 * 8) = pk.u;
    return;
  }

  // ---- V build: 256 rows/block over all 16384 output rows ----
  if (t < NC) lcnt[t] = 0.0f;
  __syncthreads();
  int gid = (b - 1024) * 256 + t;
  float p[16];
  p[10] = 1.0f; p[11] = 0.f; p[12] = 0.f; p[13] = 0.f; p[14] = 0.f; p[15] = 0.f;
  if (gid < NLB) {
    int idx = 0;
#pragma unroll
    for (int c = 0; c < NC; ++c) {
      p[c] = onehot[(size_t)gid * NC + c];
      if (p[c] == 1.0f) idx = c;
    }
    atomicAdd(&lcnt[idx], 1.0f);
  } else {
    // duplicate rows (gid >= NLB+NULB) recompute from r - NULB; no counting
    int r = (gid < NLB + NULB) ? (gid - NLB) : (gid - NLB - NULB);
    bool count = (gid < NLB + NULB);
    float a[NC], bb[NC];
#pragma unroll
    for (int c = 0; c < NC; ++c) { a[c] = l1[(size_t)r * NC + c]; bb[c] = l2[(size_t)r * NC + c]; }
    float m1 = a[0], m2 = bb[0];
#pragma unroll
    for (int c = 1; c < NC; ++c) { m1 = fmaxf(m1, a[c]); m2 = fmaxf(m2, bb[c]); }
    float s1 = 0.0f, s2 = 0.0f;
#pragma unroll
    for (int c = 0; c < NC; ++c) {
      s1 += expf(2.0f * (a[c] - m1));
      s2 += expf(2.0f * (bb[c] - m2));
    }
    bool take1 = (s1 <= s2);  // max(prob1)=1/s1 >= 1/s2=max(prob2)
    float g[NC];
#pragma unroll
    for (int c = 0; c < NC; ++c) g[c] = take1 ? a[c] : bb[c];
    float mg = g[0];
#pragma unroll
    for (int c = 1; c < NC; ++c) mg = fmaxf(mg, g[c]);
    float e[NC]; float sg = 0.0f;
#pragma unroll
    for (int c = 0; c < NC; ++c) { e[c] = expf(g[c] - mg); sg += e[c]; }
    float msk[NC];
#pragma unroll
    for (int c = 0; c < NC; ++c) msk[c] = ((e[c] / sg) >= 0.95f) ? g[c] : 0.0f;
    float mx = msk[0]; int mi = 0;
#pragma unroll
    for (int c = 1; c < NC; ++c) if (msk[c] > mx) { mx = msk[c]; mi = c; }
    if (count && mx != 0.0f) atomicAdd(&lcnt[mi], 2.0f);
    float mm = 2.0f * msk[0];
#pragma unroll
    for (int c = 1; c < NC; ++c) mm = fmaxf(mm, 2.0f * msk[c]);
    float q[NC]; float sp = 0.0f;
#pragma unroll
    for (int c = 0; c < NC; ++c) { q[c] = expf(2.0f * msk[c] - mm); sp += q[c]; }
#pragma unroll
    for (int c = 0; c < NC; ++c) p[c] = q[c] / sp;
  }
#pragma unroll
  for (int c = 0; c < 16; ++c) Vtmp[t * 16 + c] = p[c];
  __syncthreads();
  if (t < NC) atomicAdd(&cls[t], lcnt[t]);
  // scatter to VF frag layout: 1024 16B chunks, 4 per thread (coalesced)
  int gbase = (b - 1024) * 16;
#pragma unroll
  for (int u = 0; u < 4; ++u) {
    int cid = t * 4 + u;         // 0..1023
    int gl = cid >> 6;           // local group 0..15
    int l  = cid & 63;
    int q  = l >> 4;
    int n  = l & 15;
    union { bf16_t h[8]; uint4 uu; } pk;
#pragma unroll
    for (int d = 0; d < 4; ++d) {
      float v = Vtmp[(gl * 16 + q * 4 + d) * 16 + n];
      bf16_t hi = (bf16_t)v;
      pk.h[d] = hi;
      pk.h[4 + d] = (bf16_t)(v - (float)hi);
    }
    *(uint4*)(VF + ((size_t)(gbase + gl) * 64 + l) * 8) = pk.uu;
  }
}

// ================= attention + inline finalize =================
// 4 waves/block, each wave 64 stationary i-rows (4 B-frag sets).
// QK: mfma_16x16x32_bf16 from XOR-swizzled LDS. P exits in C-layout
// (lane(q,r) reg rg -> P[j=q*4+rg][i=r]) == A-operand layout at k=q*8+{0..3}.
// PV: ONE mfma per s with P replicated {w0..3,w0..3} against interleaved
// V frags {hi0..3, lo0..3} -> exact hi/lo compensated product.
// Last-arriving segment block per i-block finalizes (counter + agent atomics).
__launch_bounds__(256, 4)
__global__ void kattn(const bf16_t* __restrict__ F, const bf16_t* __restrict__ VF,
                      float* __restrict__ P12, float* __restrict__ cls,
                      int* __restrict__ cnt, float* __restrict__ out) {
  __shared__ bf16_t Fs[BJ * 128];        // 32 KB, 16B-chunk XOR swizzle
  __shared__ bf16_t Vs[(BJ / 16) * 64 * 8];  // 8 KB interleaved hi/lo frags
  __shared__ int lastflag;
  int t = threadIdx.x;
  int lane = t & 63;
  int wave = t >> 6;    // 0..3
  int q = lane >> 4;    // 0..3
  int r = lane & 15;    // 0..15
  int i0 = blockIdx.x * BI + wave * 64;
  int jbase = blockIdx.y * JSEG;

  // stationary B-frags: 4 i-sets x 16 rows
  bf16x8 bfr[4][4];
#pragma unroll
  for (int s = 0; s < 4; ++s)
#pragma unroll
    for (int kk = 0; kk < 4; ++kk)
      bfr[s][kk] = *(const bf16x8*)(F + (size_t)(i0 + s * 16 + r) * DD + kk * 32 + q * 8);

  f32x4 acc[4];
#pragma unroll
  for (int s = 0; s < 4; ++s) acc[s] = (f32x4){0.f, 0.f, 0.f, 0.f};

  const float C = 2.8853900817779268f;  // 2*log2(e): exp(2x) = 2^(Cx)

  for (int jt = 0; jt < JSEG; jt += BJ) {
    int j0 = jbase + jt;
    __syncthreads();
    // stage F tile: 2048 16B chunks, XOR-swizzled (phys chunk = col ^ (row&15))
#pragma unroll
    for (int it = 0; it < 8; ++it) {
      int cid = t + it * 256;          // 0..2047
      int row = cid >> 4;
      int col = cid & 15;
      uint4 dat = *(const uint4*)(F + (size_t)(j0 + row) * DD + col * 8);
      *(uint4*)&Fs[(row * 16 + (col ^ (row & 15))) * 8] = dat;
    }
    // stage V frags: 8 groups x 1 KB = 512 float4
    {
      int g0 = j0 >> 4;
      ((float4*)Vs)[t] = ((const float4*)(VF + (size_t)g0 * 512))[t];
      ((float4*)Vs)[t + 256] = ((const float4*)(VF + (size_t)g0 * 512))[t + 256];
    }
    __syncthreads();

#pragma unroll
    for (int jj = 0; jj < BJ / 16; ++jj) {
      // A-frags for this 16-row j-chunk (shared across the 4 i-sets)
      bf16x8 afr[4];
      const bf16_t* fsrow = &Fs[(jj * 16 + r) * 128];
#pragma unroll
      for (int kk = 0; kk < 4; ++kk)
        afr[kk] = *(const bf16x8*)(fsrow + ((kk * 4 + q) ^ r) * 8);
      f32x4 cfr[4];
#pragma unroll
      for (int s = 0; s < 4; ++s) {
        cfr[s] = (f32x4){0.f, 0.f, 0.f, 0.f};
#pragma unroll
        for (int kk = 0; kk < 4; ++kk)
          cfr[s] = __builtin_amdgcn_mfma_f32_16x16x32_bf16(afr[kk], bfr[s][kk], cfr[s], 0, 0, 0);
      }
      // V B-frag (hi at k-idx 0..3, lo at 4..7) for this j-chunk
      bf16x8 bv = *(const bf16x8*)&Vs[(jj * 64 + lane) * 8];
      // P-frags replicated {w0..3, w0..3}: one MFMA = hi+lo compensated PV
#pragma unroll
      for (int s = 0; s < 4; ++s) {
        float w0 = __builtin_amdgcn_exp2f(cfr[s][0] * C);
        float w1 = __builtin_amdgcn_exp2f(cfr[s][1] * C);
        float w2 = __builtin_amdgcn_exp2f(cfr[s][2] * C);
        float w3 = __builtin_amdgcn_exp2f(cfr[s][3] * C);
        bf16_t b0 = (bf16_t)w0, b1 = (bf16_t)w1, b2 = (bf16_t)w2, b3 = (bf16_t)w3;
        bf16x8 pf = {b0, b1, b2, b3, b0, b1, b2, b3};
        acc[s] = __builtin_amdgcn_mfma_f32_16x16x32_bf16(pf, bv, acc[s], 0, 0, 0);
      }
    }
  }

  // acc[s] lane(q,r) reg rg = partial[row = i0+s*16+q*4+rg][col = r]
  if (r < 11) {
#pragma unroll
    for (int s = 0; s < 4; ++s) {
      float* op = P12 + (size_t)(i0 + s * 16 + q * 4) * VW + r;
      atomicAdd(&op[0 * VW], acc[s][0]);
      atomicAdd(&op[1 * VW], acc[s][1]);
      atomicAdd(&op[2 * VW], acc[s][2]);
      atomicAdd(&op[3 * VW], acc[s][3]);
    }
  }

  // ---- arrival counter; last segment-block for this i-block finalizes ----
  __threadfence();
  __syncthreads();
  if (t == 0) {
    int old = __hip_atomic_fetch_add(&cnt[blockIdx.x], 1, __ATOMIC_ACQ_REL,
                                     __HIP_MEMORY_SCOPE_AGENT);
    lastflag = (old == SEG - 1);
  }
  __syncthreads();
  if (lastflag) {
    int row = blockIdx.x * BI + t;   // 256 rows, one per thread
    float d[NC]; float tot = 0.0f;
#pragma unroll
    for (int c = 0; c < NC; ++c) { d[c] = cls[c]; tot += d[c]; }
    const float* pr = P12 + (size_t)row * VW;
    float num[11];
#pragma unroll
    for (int c = 0; c < 11; ++c)
      num[c] = __hip_atomic_load(&pr[c], __ATOMIC_RELAXED, __HIP_MEMORY_SCOPE_AGENT);
    float rs = 1.0f / num[10];
    float* op = out + (size_t)row * NC;
#pragma unroll
    for (int c = 0; c < NC; ++c) {
      float den = (d[c] == 0.0f) ? tot : d[c];
      op[c] = num[c] * rs / den;
    }
  }
}

extern "C" void kernel_launch(void* const* d_in, const int* in_sizes, int n_in,
                              void* d_out, int out_size, void* d_ws, size_t ws_size,
                              hipStream_t stream) {
  const float* anchor   = (const float*)d_in[0];  // 6144x128
  const float* positive = (const float*)d_in[1];  // 6144x128
  const float* lbfeat   = (const float*)d_in[2];  // 4096x128
  const float* onehot   = (const float*)d_in[3];  // 4096x10
  const float* l1       = (const float*)d_in[4];  // 6144x10
  const float* l2       = (const float*)d_in[5];  // 6144x10
  float* out = (float*)d_out;                     // 16384x10

  char* ws = (char*)d_ws;
  bf16_t* F   = (bf16_t*)ws;                                   // 4 MiB
  bf16_t* VF  = (bf16_t*)(ws + 4194304);                       // 1024*64*16B = 1 MiB
  float*  P12 = (float*)(ws + 4194304 + 1048576);              // 768 KiB
  float*  cls = (float*)(ws + 4194304 + 1048576 + 786432);     // 64 B
  int*    cnt = (int*)(ws + 4194304 + 1048576 + 786432 + 64);  // 256 B

  hipMemsetAsync(P12, 0, 786432 + 64 + 256, stream);  // P12 + cls + cnt
  kprep2<<<1088, 256, 0, stream>>>(lbfeat, anchor, positive, onehot, l1, l2, F, VF, cls);
  kattn<<<dim3(NROWS / BI, SEG), 256, 0, stream>>>(F, VF, P12, cls, cnt, out);
}

// Round 6
// 240.854 us; speedup vs baseline: 1.0043x; 1.0043x over previous
//
#include <hip/hip_runtime.h>
#include <hip/hip_bf16.h>

#define NLB 4096
#define NULB 6144
#define NROWS 16384   // 4096 + 2*6144
#define DD 128
#define NC 10
#define VW 12                // P12 row width: 10 numerators + denom + pad
#define SEG 16
#define JSEG (NROWS / SEG)   // 1024
#define BI 256               // i-rows per block (4 waves x 64)
#define BJ 128               // j-rows per LDS tile

typedef __bf16 bf16_t;
typedef bf16_t bf16x8 __attribute__((ext_vector_type(8)));
typedef float f32x4 __attribute__((ext_vector_type(4)));
typedef unsigned int u32;

// ================= fused prep =================
// blocks 0..1023   : L2-normalize 16 rows each of [lb;anchor;pos] -> bf16 F
// blocks 1024..1087: build V fragments (interleaved hi/lo bf16) + class counts
// VF layout: group g (16 j-rows), lane l=(q=l>>4, n=l&15), 16B chunk:
//   bytes 0..7 : hi bf16 of V[g*16+q*4+d][n], d=0..3
//   bytes 8..15: lo bf16 (v - hi) of same  -> B-operand frag k=q*8+{0..7}
__global__ void kprep2(const float* __restrict__ lb, const float* __restrict__ an,
                       const float* __restrict__ po, const float* __restrict__ onehot,
                       const float* __restrict__ l1, const float* __restrict__ l2,
                       bf16_t* __restrict__ F, bf16_t* __restrict__ VF,
                       float* __restrict__ cls) {
  __shared__ float Vtmp[256 * 16];
  __shared__ float lcnt[NC];
  int b = blockIdx.x;
  int t = threadIdx.x;

  if (b < 1024) {
    // ---- normalize: 16 rows/block, 16 lanes/row, 8 floats/lane ----
    int row = b * 16 + (t >> 4);
    int l16 = t & 15;
    const float* src;
    if (row < NLB) src = lb + (size_t)row * DD;
    else if (row < NLB + NULB) src = an + (size_t)(row - NLB) * DD;
    else src = po + (size_t)(row - NLB - NULB) * DD;
    float4 v0 = ((const float4*)src)[l16 * 2];
    float4 v1 = ((const float4*)src)[l16 * 2 + 1];
    float ss = v0.x*v0.x + v0.y*v0.y + v0.z*v0.z + v0.w*v0.w
             + v1.x*v1.x + v1.y*v1.y + v1.z*v1.z + v1.w*v1.w;
#pragma unroll
    for (int off = 8; off >= 1; off >>= 1) ss += __shfl_xor(ss, off);
    float inv = 1.0f / fmaxf(sqrtf(ss), 1e-12f);
    union { bf16_t h[8]; uint4 u; } pk;
    pk.h[0] = (bf16_t)(v0.x*inv); pk.h[1] = (bf16_t)(v0.y*inv);
    pk.h[2] = (bf16_t)(v0.z*inv); pk.h[3] = (bf16_t)(v0.w*inv);
    pk.h[4] = (bf16_t)(v1.x*inv); pk.h[5] = (bf16_t)(v1.y*inv);
    pk.h[6] = (bf16_t)(v1.z*inv); pk.h[7] = (bf16_t)(v1.w*inv);
    *(uint4*)(F + (size_t)row * DD + l16 * 8) = pk.u;
    return;
  }

  // ---- V build: 256 rows/block over all 16384 output rows ----
  if (t < NC) lcnt[t] = 0.0f;
  __syncthreads();
  int gid = (b - 1024) * 256 + t;
  float p[16];
  p[10] = 1.0f; p[11] = 0.f; p[12] = 0.f; p[13] = 0.f; p[14] = 0.f; p[15] = 0.f;
  if (gid < NLB) {
    int idx = 0;
#pragma unroll
    for (int c = 0; c < NC; ++c) {
      p[c] = onehot[(size_t)gid * NC + c];
      if (p[c] == 1.0f) idx = c;
    }
    atomicAdd(&lcnt[idx], 1.0f);
  } else {
    // duplicate rows (gid >= NLB+NULB) recompute from r - NULB; no counting
    int r = (gid < NLB + NULB) ? (gid - NLB) : (gid - NLB - NULB);
    bool count = (gid < NLB + NULB);
    float a[NC], bb[NC];
#pragma unroll
    for (int c = 0; c < NC; ++c) { a[c] = l1[(size_t)r * NC + c]; bb[c] = l2[(size_t)r * NC + c]; }
    float m1 = a[0], m2 = bb[0];
#pragma unroll
    for (int c = 1; c < NC; ++c) { m1 = fmaxf(m1, a[c]); m2 = fmaxf(m2, bb[c]); }
    float s1 = 0.0f, s2 = 0.0f;
#pragma unroll
    for (int c = 0; c < NC; ++c) {
      s1 += expf(2.0f * (a[c] - m1));
      s2 += expf(2.0f * (bb[c] - m2));
    }
    bool take1 = (s1 <= s2);  // max(prob1)=1/s1 >= 1/s2=max(prob2)
    float g[NC];
#pragma unroll
    for (int c = 0; c < NC; ++c) g[c] = take1 ? a[c] : bb[c];
    float mg = g[0];
#pragma unroll
    for (int c = 1; c < NC; ++c) mg = fmaxf(mg, g[c]);
    float e[NC]; float sg = 0.0f;
#pragma unroll
    for (int c = 0; c < NC; ++c) { e[c] = expf(g[c] - mg); sg += e[c]; }
    float msk[NC];
#pragma unroll
    for (int c = 0; c < NC; ++c) msk[c] = ((e[c] / sg) >= 0.95f) ? g[c] : 0.0f;
    float mx = msk[0]; int mi = 0;
#pragma unroll
    for (int c = 1; c < NC; ++c) if (msk[c] > mx) { mx = msk[c]; mi = c; }
    if (count && mx != 0.0f) atomicAdd(&lcnt[mi], 2.0f);
    float mm = 2.0f * msk[0];
#pragma unroll
    for (int c = 1; c < NC; ++c) mm = fmaxf(mm, 2.0f * msk[c]);
    float q[NC]; float sp = 0.0f;
#pragma unroll
    for (int c = 0; c < NC; ++c) { q[c] = expf(2.0f * msk[c] - mm); sp += q[c]; }
#pragma unroll
    for (int c = 0; c < NC; ++c) p[c] = q[c] / sp;
  }
#pragma unroll
  for (int c = 0; c < 16; ++c) Vtmp[t * 16 + c] = p[c];
  __syncthreads();
  if (t < NC) atomicAdd(&cls[t], lcnt[t]);
  // scatter to VF frag layout: 1024 16B chunks, 4 per thread (coalesced)
  int gbase = (b - 1024) * 16;
#pragma unroll
  for (int u = 0; u < 4; ++u) {
    int cid = t * 4 + u;         // 0..1023
    int gl = cid >> 6;           // local group 0..15
    int l  = cid & 63;
    int q  = l >> 4;
    int n  = l & 15;
    union { bf16_t h[8]; uint4 uu; } pk;
#pragma unroll
    for (int d = 0; d < 4; ++d) {
      float v = Vtmp[(gl * 16 + q * 4 + d) * 16 + n];
      bf16_t hi = (bf16_t)v;
      pk.h[d] = hi;
      pk.h[4 + d] = (bf16_t)(v - (float)hi);
    }
    *(uint4*)(VF + ((size_t)(gbase + gl) * 64 + l) * 8) = pk.uu;
  }
}

// ================= attention + inline finalize =================
// 4 waves/block, each wave 64 stationary i-rows (4 B-frag sets).
// QK: mfma_16x16x32_bf16 from XOR-swizzled LDS. P exits in C-layout
// (lane(q,r) reg rg -> P[j=q*4+rg][i=r]) == A-operand layout at k=q*8+{0..3}.
// PV: ONE mfma per s with P replicated {w0..3,w0..3} against interleaved
// V frags {hi0..3, lo0..3} -> exact hi/lo compensated product.
// LDS exactly 40960 B (arrival flag aliased into Vs) -> 4 blocks/CU,
// grid 1024 = 4 x 256 CUs: ALL blocks resident in one round, no tail.
__launch_bounds__(256, 4)
__global__ void kattn(const bf16_t* __restrict__ F, const bf16_t* __restrict__ VF,
                      float* __restrict__ P12, float* __restrict__ cls,
                      int* __restrict__ cnt, float* __restrict__ out) {
  __shared__ bf16_t Fs[BJ * 128];            // 32 KB, 16B-chunk XOR swizzle
  __shared__ bf16_t Vs[(BJ / 16) * 64 * 8];  // 8 KB interleaved hi/lo frags
  int t = threadIdx.x;
  int lane = t & 63;
  int wave = t >> 6;    // 0..3
  int q = lane >> 4;    // 0..3
  int r = lane & 15;    // 0..15
  int i0 = blockIdx.x * BI + wave * 64;
  int jbase = blockIdx.y * JSEG;

  // stationary B-frags: 4 i-sets x 16 rows
  bf16x8 bfr[4][4];
#pragma unroll
  for (int s = 0; s < 4; ++s)
#pragma unroll
    for (int kk = 0; kk < 4; ++kk)
      bfr[s][kk] = *(const bf16x8*)(F + (size_t)(i0 + s * 16 + r) * DD + kk * 32 + q * 8);

  f32x4 acc[4];
#pragma unroll
  for (int s = 0; s < 4; ++s) acc[s] = (f32x4){0.f, 0.f, 0.f, 0.f};

  const float C = 2.8853900817779268f;  // 2*log2(e): exp(2x) = 2^(Cx)

  for (int jt = 0; jt < JSEG; jt += BJ) {
    int j0 = jbase + jt;
    __syncthreads();
    // stage F tile: 2048 16B chunks, XOR-swizzled (phys chunk = col ^ (row&15))
#pragma unroll
    for (int it = 0; it < 8; ++it) {
      int cid = t + it * 256;          // 0..2047
      int row = cid >> 4;
      int col = cid & 15;
      uint4 dat = *(const uint4*)(F + (size_t)(j0 + row) * DD + col * 8);
      *(uint4*)&Fs[(row * 16 + (col ^ (row & 15))) * 8] = dat;
    }
    // stage V frags: 8 groups x 1 KB = 512 float4
    {
      int g0 = j0 >> 4;
      ((float4*)Vs)[t] = ((const float4*)(VF + (size_t)g0 * 512))[t];
      ((float4*)Vs)[t + 256] = ((const float4*)(VF + (size_t)g0 * 512))[t + 256];
    }
    __syncthreads();

#pragma unroll
    for (int jj = 0; jj < BJ / 16; ++jj) {
      // A-frags for this 16-row j-chunk (shared across the 4 i-sets)
      bf16x8 afr[4];
      const bf16_t* fsrow = &Fs[(jj * 16 + r) * 128];
#pragma unroll
      for (int kk = 0; kk < 4; ++kk)
        afr[kk] = *(const bf16x8*)(fsrow + ((kk * 4 + q) ^ r) * 8);
      f32x4 cfr[4];
#pragma unroll
      for (int s = 0; s < 4; ++s) {
        cfr[s] = (f32x4){0.f, 0.f, 0.f, 0.f};
#pragma unroll
        for (int kk = 0; kk < 4; ++kk)
          cfr[s] = __builtin_amdgcn_mfma_f32_16x16x32_bf16(afr[kk], bfr[s][kk], cfr[s], 0, 0, 0);
      }
      // V B-frag (hi at k-idx 0..3, lo at 4..7) for this j-chunk
      bf16x8 bv = *(const bf16x8*)&Vs[(jj * 64 + lane) * 8];
      // P-frags replicated {w0..3, w0..3}: one MFMA = hi+lo compensated PV
#pragma unroll
      for (int s = 0; s < 4; ++s) {
        float w0 = __builtin_amdgcn_exp2f(cfr[s][0] * C);
        float w1 = __builtin_amdgcn_exp2f(cfr[s][1] * C);
        float w2 = __builtin_amdgcn_exp2f(cfr[s][2] * C);
        float w3 = __builtin_amdgcn_exp2f(cfr[s][3] * C);
        bf16_t b0 = (bf16_t)w0, b1 = (bf16_t)w1, b2 = (bf16_t)w2, b3 = (bf16_t)w3;
        bf16x8 pf = {b0, b1, b2, b3, b0, b1, b2, b3};
        acc[s] = __builtin_amdgcn_mfma_f32_16x16x32_bf16(pf, bv, acc[s], 0, 0, 0);
      }
    }
  }

  // acc[s] lane(q,r) reg rg = partial[row = i0+s*16+q*4+rg][col = r]
  if (r < 11) {
#pragma unroll
    for (int s = 0; s < 4; ++s) {
      float* op = P12 + (size_t)(i0 + s * 16 + q * 4) * VW + r;
      atomicAdd(&op[0 * VW], acc[s][0]);
      atomicAdd(&op[1 * VW], acc[s][1]);
      atomicAdd(&op[2 * VW], acc[s][2]);
      atomicAdd(&op[3 * VW], acc[s][3]);
    }
  }

  // ---- arrival counter; last segment-block for this i-block finalizes ----
  // flag lives in Vs (dead after the last tile) to keep LDS at exactly 40960.
  volatile int* flagp = (volatile int*)Vs;
  __threadfence();
  __syncthreads();
  if (t == 0) {
    int old = __hip_atomic_fetch_add(&cnt[blockIdx.x], 1, __ATOMIC_ACQ_REL,
                                     __HIP_MEMORY_SCOPE_AGENT);
    *flagp = (old == SEG - 1);
  }
  __syncthreads();
  if (*flagp) {
    int row = blockIdx.x * BI + t;   // 256 rows, one per thread
    float d[NC]; float tot = 0.0f;
#pragma unroll
    for (int c = 0; c < NC; ++c) { d[c] = cls[c]; tot += d[c]; }
    const float* pr = P12 + (size_t)row * VW;
    float num[11];
#pragma unroll
    for (int c = 0; c < 11; ++c)
      num[c] = __hip_atomic_load(&pr[c], __ATOMIC_RELAXED, __HIP_MEMORY_SCOPE_AGENT);
    float rs = 1.0f / num[10];
    float* op = out + (size_t)row * NC;
#pragma unroll
    for (int c = 0; c < NC; ++c) {
      float den = (d[c] == 0.0f) ? tot : d[c];
      op[c] = num[c] * rs / den;
    }
  }
}

extern "C" void kernel_launch(void* const* d_in, const int* in_sizes, int n_in,
                              void* d_out, int out_size, void* d_ws, size_t ws_size,
                              hipStream_t stream) {
  const float* anchor   = (const float*)d_in[0];  // 6144x128
  const float* positive = (const float*)d_in[1];  // 6144x128
  const float* lbfeat   = (const float*)d_in[2];  // 4096x128
  const float* onehot   = (const float*)d_in[3];  // 4096x10
  const float* l1       = (const float*)d_in[4];  // 6144x10
  const float* l2       = (const float*)d_in[5];  // 6144x10
  float* out = (float*)d_out;                     // 16384x10

  char* ws = (char*)d_ws;
  bf16_t* F   = (bf16_t*)ws;                                   // 4 MiB
  bf16_t* VF  = (bf16_t*)(ws + 4194304);                       // 1024*64*16B = 1 MiB
  float*  P12 = (float*)(ws + 4194304 + 1048576);              // 768 KiB
  float*  cls = (float*)(ws + 4194304 + 1048576 + 786432);     // 64 B
  int*    cnt = (int*)(ws + 4194304 + 1048576 + 786432 + 64);  // 256 B

  hipMemsetAsync(P12, 0, 786432 + 64 + 256, stream);  // P12 + cls + cnt
  kprep2<<<1088, 256, 0, stream>>>(lbfeat, anchor, positive, onehot, l1, l2, F, VF, cls);
  kattn<<<dim3(NROWS / BI, SEG), 256, 0, stream>>>(F, VF, P12, cls, cnt, out);
}

// Round 7
// 160.877 us; speedup vs baseline: 1.5036x; 1.4971x over previous
//
#include <hip/hip_runtime.h>
#include <hip/hip_bf16.h>

#define NLB 4096
#define NULB 6144
#define NROWS 16384   // 4096 + 2*6144
#define DD 128
#define NC 10
#define VW 12                // P12 row width: 10 numerators + denom + pad
#define SEG 16
#define JSEG (NROWS / SEG)   // 1024
#define BI 256               // i-rows per block (4 waves x 64)
#define BJ 128               // j-rows per LDS tile

typedef __bf16 bf16_t;
typedef bf16_t bf16x8 __attribute__((ext_vector_type(8)));
typedef float f32x4 __attribute__((ext_vector_type(4)));
typedef unsigned int u32;

// ================= fused prep =================
// blocks 0..1023   : L2-normalize 16 rows each of [lb;anchor;pos] -> bf16 F
// blocks 1024..1087: build V fragments (interleaved hi/lo bf16) + class counts
// VF layout: group g (16 j-rows), lane l=(q=l>>4, n=l&15), 16B chunk:
//   bytes 0..7 : hi bf16 of V[g*16+q*4+d][n], d=0..3
//   bytes 8..15: lo bf16 (v - hi) of same  -> B-operand frag k=q*8+{0..7}
__global__ void kprep2(const float* __restrict__ lb, const float* __restrict__ an,
                       const float* __restrict__ po, const float* __restrict__ onehot,
                       const float* __restrict__ l1, const float* __restrict__ l2,
                       bf16_t* __restrict__ F, bf16_t* __restrict__ VF,
                       float* __restrict__ cls) {
  __shared__ float Vtmp[256 * 16];
  __shared__ float lcnt[NC];
  int b = blockIdx.x;
  int t = threadIdx.x;

  if (b < 1024) {
    // ---- normalize: 16 rows/block, 16 lanes/row, 8 floats/lane ----
    int row = b * 16 + (t >> 4);
    int l16 = t & 15;
    const float* src;
    if (row < NLB) src = lb + (size_t)row * DD;
    else if (row < NLB + NULB) src = an + (size_t)(row - NLB) * DD;
    else src = po + (size_t)(row - NLB - NULB) * DD;
    float4 v0 = ((const float4*)src)[l16 * 2];
    float4 v1 = ((const float4*)src)[l16 * 2 + 1];
    float ss = v0.x*v0.x + v0.y*v0.y + v0.z*v0.z + v0.w*v0.w
             + v1.x*v1.x + v1.y*v1.y + v1.z*v1.z + v1.w*v1.w;
#pragma unroll
    for (int off = 8; off >= 1; off >>= 1) ss += __shfl_xor(ss, off);
    float inv = 1.0f / fmaxf(sqrtf(ss), 1e-12f);
    union { bf16_t h[8]; uint4 u; } pk;
    pk.h[0] = (bf16_t)(v0.x*inv); pk.h[1] = (bf16_t)(v0.y*inv);
    pk.h[2] = (bf16_t)(v0.z*inv); pk.h[3] = (bf16_t)(v0.w*inv);
    pk.h[4] = (bf16_t)(v1.x*inv); pk.h[5] = (bf16_t)(v1.y*inv);
    pk.h[6] = (bf16_t)(v1.z*inv); pk.h[7] = (bf16_t)(v1.w*inv);
    *(uint4*)(F + (size_t)row * DD + l16 * 8) = pk.u;
    return;
  }

  // ---- V build: 256 rows/block over all 16384 output rows ----
  if (t < NC) lcnt[t] = 0.0f;
  __syncthreads();
  int gid = (b - 1024) * 256 + t;
  float p[16];
  p[10] = 1.0f; p[11] = 0.f; p[12] = 0.f; p[13] = 0.f; p[14] = 0.f; p[15] = 0.f;
  if (gid < NLB) {
    int idx = 0;
#pragma unroll
    for (int c = 0; c < NC; ++c) {
      p[c] = onehot[(size_t)gid * NC + c];
      if (p[c] == 1.0f) idx = c;
    }
    atomicAdd(&lcnt[idx], 1.0f);
  } else {
    // duplicate rows (gid >= NLB+NULB) recompute from r - NULB; no counting
    int r = (gid < NLB + NULB) ? (gid - NLB) : (gid - NLB - NULB);
    bool count = (gid < NLB + NULB);
    float a[NC], bb[NC];
#pragma unroll
    for (int c = 0; c < NC; ++c) { a[c] = l1[(size_t)r * NC + c]; bb[c] = l2[(size_t)r * NC + c]; }
    float m1 = a[0], m2 = bb[0];
#pragma unroll
    for (int c = 1; c < NC; ++c) { m1 = fmaxf(m1, a[c]); m2 = fmaxf(m2, bb[c]); }
    float s1 = 0.0f, s2 = 0.0f;
#pragma unroll
    for (int c = 0; c < NC; ++c) {
      s1 += expf(2.0f * (a[c] - m1));
      s2 += expf(2.0f * (bb[c] - m2));
    }
    bool take1 = (s1 <= s2);  // max(prob1)=1/s1 >= 1/s2=max(prob2)
    float g[NC];
#pragma unroll
    for (int c = 0; c < NC; ++c) g[c] = take1 ? a[c] : bb[c];
    float mg = g[0];
#pragma unroll
    for (int c = 1; c < NC; ++c) mg = fmaxf(mg, g[c]);
    float e[NC]; float sg = 0.0f;
#pragma unroll
    for (int c = 0; c < NC; ++c) { e[c] = expf(g[c] - mg); sg += e[c]; }
    float msk[NC];
#pragma unroll
    for (int c = 0; c < NC; ++c) msk[c] = ((e[c] / sg) >= 0.95f) ? g[c] : 0.0f;
    float mx = msk[0]; int mi = 0;
#pragma unroll
    for (int c = 1; c < NC; ++c) if (msk[c] > mx) { mx = msk[c]; mi = c; }
    if (count && mx != 0.0f) atomicAdd(&lcnt[mi], 2.0f);
    float mm = 2.0f * msk[0];
#pragma unroll
    for (int c = 1; c < NC; ++c) mm = fmaxf(mm, 2.0f * msk[c]);
    float q[NC]; float sp = 0.0f;
#pragma unroll
    for (int c = 0; c < NC; ++c) { q[c] = expf(2.0f * msk[c] - mm); sp += q[c]; }
#pragma unroll
    for (int c = 0; c < NC; ++c) p[c] = q[c] / sp;
  }
#pragma unroll
  for (int c = 0; c < 16; ++c) Vtmp[t * 16 + c] = p[c];
  __syncthreads();
  if (t < NC) atomicAdd(&cls[t], lcnt[t]);
  // scatter to VF frag layout: 1024 16B chunks, 4 per thread (coalesced)
  int gbase = (b - 1024) * 16;
#pragma unroll
  for (int u = 0; u < 4; ++u) {
    int cid = t * 4 + u;         // 0..1023
    int gl = cid >> 6;           // local group 0..15
    int l  = cid & 63;
    int q  = l >> 4;
    int n  = l & 15;
    union { bf16_t h[8]; uint4 uu; } pk;
#pragma unroll
    for (int d = 0; d < 4; ++d) {
      float v = Vtmp[(gl * 16 + q * 4 + d) * 16 + n];
      bf16_t hi = (bf16_t)v;
      pk.h[d] = hi;
      pk.h[4 + d] = (bf16_t)(v - (float)hi);
    }
    *(uint4*)(VF + ((size_t)(gbase + gl) * 64 + l) * 8) = pk.uu;
  }
}

// ================= attention partials =================
// 4 waves/block, each wave 64 stationary i-rows (4 B-frag sets).
// QK: mfma_16x16x32_bf16 from XOR-swizzled LDS. P exits in C-layout
// (lane(q,r) reg rg -> P[j=q*4+rg][i=r]) == A-operand layout at k=q*8+{0..3}.
// PV: ONE mfma per s with P replicated {w0..3,w0..3} against interleaved
// V frags {hi0..3, lo0..3} -> exact hi/lo compensated product.
// LDS exactly 40960 B -> 4 blocks/CU; grid 1024 = 4 x 256 CUs, no tail.
// NO device fence here (R5/R6 lesson: per-block __threadfence L2-writeback
// storm cost ~60 us, WRITE_SIZE 8->28 MB). Finalize is a separate kernel.
__launch_bounds__(256, 4)
__global__ void kattn(const bf16_t* __restrict__ F, const bf16_t* __restrict__ VF,
                      float* __restrict__ P12) {
  __shared__ bf16_t Fs[BJ * 128];            // 32 KB, 16B-chunk XOR swizzle
  __shared__ bf16_t Vs[(BJ / 16) * 64 * 8];  // 8 KB interleaved hi/lo frags
  int t = threadIdx.x;
  int lane = t & 63;
  int wave = t >> 6;    // 0..3
  int q = lane >> 4;    // 0..3
  int r = lane & 15;    // 0..15
  int i0 = blockIdx.x * BI + wave * 64;
  int jbase = blockIdx.y * JSEG;

  // stationary B-frags: 4 i-sets x 16 rows
  bf16x8 bfr[4][4];
#pragma unroll
  for (int s = 0; s < 4; ++s)
#pragma unroll
    for (int kk = 0; kk < 4; ++kk)
      bfr[s][kk] = *(const bf16x8*)(F + (size_t)(i0 + s * 16 + r) * DD + kk * 32 + q * 8);

  f32x4 acc[4];
#pragma unroll
  for (int s = 0; s < 4; ++s) acc[s] = (f32x4){0.f, 0.f, 0.f, 0.f};

  const float C = 2.8853900817779268f;  // 2*log2(e): exp(2x) = 2^(Cx)

  for (int jt = 0; jt < JSEG; jt += BJ) {
    int j0 = jbase + jt;
    __syncthreads();
    // stage F tile: 2048 16B chunks, XOR-swizzled (phys chunk = col ^ (row&15))
#pragma unroll
    for (int it = 0; it < 8; ++it) {
      int cid = t + it * 256;          // 0..2047
      int row = cid >> 4;
      int col = cid & 15;
      uint4 dat = *(const uint4*)(F + (size_t)(j0 + row) * DD + col * 8);
      *(uint4*)&Fs[(row * 16 + (col ^ (row & 15))) * 8] = dat;
    }
    // stage V frags: 8 groups x 1 KB = 512 float4
    {
      int g0 = j0 >> 4;
      ((float4*)Vs)[t] = ((const float4*)(VF + (size_t)g0 * 512))[t];
      ((float4*)Vs)[t + 256] = ((const float4*)(VF + (size_t)g0 * 512))[t + 256];
    }
    __syncthreads();

#pragma unroll
    for (int jj = 0; jj < BJ / 16; ++jj) {
      // A-frags for this 16-row j-chunk (shared across the 4 i-sets)
      bf16x8 afr[4];
      const bf16_t* fsrow = &Fs[(jj * 16 + r) * 128];
#pragma unroll
      for (int kk = 0; kk < 4; ++kk)
        afr[kk] = *(const bf16x8*)(fsrow + ((kk * 4 + q) ^ r) * 8);
      f32x4 cfr[4];
#pragma unroll
      for (int s = 0; s < 4; ++s) {
        cfr[s] = (f32x4){0.f, 0.f, 0.f, 0.f};
#pragma unroll
        for (int kk = 0; kk < 4; ++kk)
          cfr[s] = __builtin_amdgcn_mfma_f32_16x16x32_bf16(afr[kk], bfr[s][kk], cfr[s], 0, 0, 0);
      }
      // V B-frag (hi at k-idx 0..3, lo at 4..7) for this j-chunk
      bf16x8 bv = *(const bf16x8*)&Vs[(jj * 64 + lane) * 8];
      // P-frags replicated {w0..3, w0..3}: one MFMA = hi+lo compensated PV
#pragma unroll
      for (int s = 0; s < 4; ++s) {
        float w0 = __builtin_amdgcn_exp2f(cfr[s][0] * C);
        float w1 = __builtin_amdgcn_exp2f(cfr[s][1] * C);
        float w2 = __builtin_amdgcn_exp2f(cfr[s][2] * C);
        float w3 = __builtin_amdgcn_exp2f(cfr[s][3] * C);
        bf16_t b0 = (bf16_t)w0, b1 = (bf16_t)w1, b2 = (bf16_t)w2, b3 = (bf16_t)w3;
        bf16x8 pf = {b0, b1, b2, b3, b0, b1, b2, b3};
        acc[s] = __builtin_amdgcn_mfma_f32_16x16x32_bf16(pf, bv, acc[s], 0, 0, 0);
      }
    }
  }

  // acc[s] lane(q,r) reg rg = partial[row = i0+s*16+q*4+rg][col = r]
  if (r < 11) {
#pragma unroll
    for (int s = 0; s < 4; ++s) {
      float* op = P12 + (size_t)(i0 + s * 16 + q * 4) * VW + r;
      atomicAdd(&op[0 * VW], acc[s][0]);
      atomicAdd(&op[1 * VW], acc[s][1]);
      atomicAdd(&op[2 * VW], acc[s][2]);
      atomicAdd(&op[3 * VW], acc[s][3]);
    }
  }
}

// ---------------- finalize: divide by softmax denom and class denom ----------------
__global__ void kfinal(float* __restrict__ out, const float* __restrict__ P12,
                       const float* __restrict__ cls) {
  int row = blockIdx.x * 256 + threadIdx.x;  // 64 blocks x 256
  float d[NC]; float tot = 0.0f;
#pragma unroll
  for (int c = 0; c < NC; ++c) { d[c] = cls[c]; tot += d[c]; }
  const float* pr = P12 + (size_t)row * VW;
  float rs = 1.0f / pr[10];
  float* op = out + (size_t)row * NC;
#pragma unroll
  for (int c = 0; c < NC; ++c) {
    float den = (d[c] == 0.0f) ? tot : d[c];
    op[c] = pr[c] * rs / den;
  }
}

extern "C" void kernel_launch(void* const* d_in, const int* in_sizes, int n_in,
                              void* d_out, int out_size, void* d_ws, size_t ws_size,
                              hipStream_t stream) {
  const float* anchor   = (const float*)d_in[0];  // 6144x128
  const float* positive = (const float*)d_in[1];  // 6144x128
  const float* lbfeat   = (const float*)d_in[2];  // 4096x128
  const float* onehot   = (const float*)d_in[3];  // 4096x10
  const float* l1       = (const float*)d_in[4];  // 6144x10
  const float* l2       = (const float*)d_in[5];  // 6144x10
  float* out = (float*)d_out;                     // 16384x10

  char* ws = (char*)d_ws;
  bf16_t* F   = (bf16_t*)ws;                                   // 4 MiB
  bf16_t* VF  = (bf16_t*)(ws + 4194304);                       // 1024*64*16B = 1 MiB
  float*  P12 = (float*)(ws + 4194304 + 1048576);              // 768 KiB
  float*  cls = (float*)(ws + 4194304 + 1048576 + 786432);     // 64 B

  hipMemsetAsync(P12, 0, 786432 + 64, stream);  // P12 + cls
  kprep2<<<1088, 256, 0, stream>>>(lbfeat, anchor, positive, onehot, l1, l2, F, VF, cls);
  kattn<<<dim3(NROWS / BI, SEG), 256, 0, stream>>>(F, VF, P12);
  kfinal<<<NROWS / 256, 256, 0, stream>>>(out, P12, cls);
}

// Round 8
// 143.293 us; speedup vs baseline: 1.6881x; 1.1227x over previous
//
#include <hip/hip_runtime.h>
#include <hip/hip_bf16.h>

#define NLB 4096
#define NULB 6144
#define NROWS 16384   // 4096 + 2*6144
#define DD 128
#define NC 10
#define VW 12                // P12 row width: 10 numerators + denom + pad
#define SEG 16
#define JSEG (NROWS / SEG)   // 1024
#define BI 256               // i-rows per block (4 waves x 64)
#define BJ 128               // j-rows per LDS tile
#define SQRTC 1.6986437f     // sqrt(2*log2(e)); F pre-scaled so exp(2*dot)=2^cfr

typedef __bf16 bf16_t;
typedef bf16_t bf16x8 __attribute__((ext_vector_type(8)));
typedef float f32x4 __attribute__((ext_vector_type(4)));
typedef unsigned int u32;

// F global layout = swizzled LDS image, 128-row tiles:
//   element index(row, chunk c0..15) =
//     (row>>7)*16384 + ((row&127)*16 + (c ^ (row&15)))*8   (8 bf16 per chunk)
// -> kattn stages a tile with contiguous global_load_lds (no VGPR round-trip),
//    and LDS-read addressing is identical to the global bfr addressing.
__device__ __forceinline__ size_t fidx(int row, int c) {
  return ((size_t)(row >> 7) << 14) + (size_t)(((row & 127) * 16 + (c ^ (row & 15))) << 3);
}

// ================= fused prep =================
// blocks 0..1023   : L2-normalize 16 rows each of [lb;anchor;pos] -> scaled bf16
//                    F (swizzled-tile layout) + zero 192 floats of P12 each
// blocks 1024..1087: build V fragments (interleaved hi/lo bf16) + per-block
//                    class-count partials (no global atomics, no pre-zero)
__global__ void kprep2(const float* __restrict__ lb, const float* __restrict__ an,
                       const float* __restrict__ po, const float* __restrict__ onehot,
                       const float* __restrict__ l1, const float* __restrict__ l2,
                       bf16_t* __restrict__ F, bf16_t* __restrict__ VF,
                       float* __restrict__ clsPart, float* __restrict__ P12) {
  __shared__ float Vtmp[256 * 16];
  __shared__ float lcnt[NC];
  int b = blockIdx.x;
  int t = threadIdx.x;

  if (b < 1024) {
    // ---- normalize: 16 rows/block, 16 lanes/row, 8 floats/lane ----
    if (t < 192) P12[(size_t)b * 192 + t] = 0.0f;  // 1024*192 = 196608 = NROWS*VW
    int row = b * 16 + (t >> 4);
    int c = t & 15;
    const float* src;
    if (row < NLB) src = lb + (size_t)row * DD;
    else if (row < NLB + NULB) src = an + (size_t)(row - NLB) * DD;
    else src = po + (size_t)(row - NLB - NULB) * DD;
    float4 v0 = ((const float4*)src)[c * 2];
    float4 v1 = ((const float4*)src)[c * 2 + 1];
    float ss = v0.x*v0.x + v0.y*v0.y + v0.z*v0.z + v0.w*v0.w
             + v1.x*v1.x + v1.y*v1.y + v1.z*v1.z + v1.w*v1.w;
#pragma unroll
    for (int off = 8; off >= 1; off >>= 1) ss += __shfl_xor(ss, off);
    float inv = SQRTC / fmaxf(sqrtf(ss), 1e-12f);
    union { bf16_t h[8]; uint4 u; } pk;
    pk.h[0] = (bf16_t)(v0.x*inv); pk.h[1] = (bf16_t)(v0.y*inv);
    pk.h[2] = (bf16_t)(v0.z*inv); pk.h[3] = (bf16_t)(v0.w*inv);
    pk.h[4] = (bf16_t)(v1.x*inv); pk.h[5] = (bf16_t)(v1.y*inv);
    pk.h[6] = (bf16_t)(v1.z*inv); pk.h[7] = (bf16_t)(v1.w*inv);
    *(uint4*)(F + fidx(row, c)) = pk.u;
    return;
  }

  // ---- V build: 256 rows/block over all 16384 output rows ----
  if (t < NC) lcnt[t] = 0.0f;
  __syncthreads();
  int gid = (b - 1024) * 256 + t;
  float p[16];
  p[10] = 1.0f; p[11] = 0.f; p[12] = 0.f; p[13] = 0.f; p[14] = 0.f; p[15] = 0.f;
  if (gid < NLB) {
    int idx = 0;
#pragma unroll
    for (int c = 0; c < NC; ++c) {
      p[c] = onehot[(size_t)gid * NC + c];
      if (p[c] == 1.0f) idx = c;
    }
    atomicAdd(&lcnt[idx], 1.0f);
  } else {
    // duplicate rows (gid >= NLB+NULB) recompute from r - NULB; no counting
    int r = (gid < NLB + NULB) ? (gid - NLB) : (gid - NLB - NULB);
    bool count = (gid < NLB + NULB);
    float a[NC], bb[NC];
#pragma unroll
    for (int c = 0; c < NC; ++c) { a[c] = l1[(size_t)r * NC + c]; bb[c] = l2[(size_t)r * NC + c]; }
    float m1 = a[0], m2 = bb[0];
#pragma unroll
    for (int c = 1; c < NC; ++c) { m1 = fmaxf(m1, a[c]); m2 = fmaxf(m2, bb[c]); }
    float s1 = 0.0f, s2 = 0.0f;
#pragma unroll
    for (int c = 0; c < NC; ++c) {
      s1 += expf(2.0f * (a[c] - m1));
      s2 += expf(2.0f * (bb[c] - m2));
    }
    bool take1 = (s1 <= s2);  // max(prob1)=1/s1 >= 1/s2=max(prob2)
    float g[NC];
#pragma unroll
    for (int c = 0; c < NC; ++c) g[c] = take1 ? a[c] : bb[c];
    float mg = g[0];
#pragma unroll
    for (int c = 1; c < NC; ++c) mg = fmaxf(mg, g[c]);
    float e[NC]; float sg = 0.0f;
#pragma unroll
    for (int c = 0; c < NC; ++c) { e[c] = expf(g[c] - mg); sg += e[c]; }
    float msk[NC];
#pragma unroll
    for (int c = 0; c < NC; ++c) msk[c] = ((e[c] / sg) >= 0.95f) ? g[c] : 0.0f;
    float mx = msk[0]; int mi = 0;
#pragma unroll
    for (int c = 1; c < NC; ++c) if (msk[c] > mx) { mx = msk[c]; mi = c; }
    if (count && mx != 0.0f) atomicAdd(&lcnt[mi], 2.0f);
    float mm = 2.0f * msk[0];
#pragma unroll
    for (int c = 1; c < NC; ++c) mm = fmaxf(mm, 2.0f * msk[c]);
    float q[NC]; float sp = 0.0f;
#pragma unroll
    for (int c = 0; c < NC; ++c) { q[c] = expf(2.0f * msk[c] - mm); sp += q[c]; }
#pragma unroll
    for (int c = 0; c < NC; ++c) p[c] = q[c] / sp;
  }
#pragma unroll
  for (int c = 0; c < 16; ++c) Vtmp[t * 16 + c] = p[c];
  __syncthreads();
  if (t < 16) clsPart[(size_t)(b - 1024) * 16 + t] = (t < NC) ? lcnt[t] : 0.0f;
  // scatter to VF frag layout: 1024 16B chunks, 4 per thread (coalesced)
  int gbase = (b - 1024) * 16;
#pragma unroll
  for (int u = 0; u < 4; ++u) {
    int cid = t * 4 + u;         // 0..1023
    int gl = cid >> 6;           // local group 0..15
    int l  = cid & 63;
    int q  = l >> 4;
    int n  = l & 15;
    union { bf16_t h[8]; uint4 uu; } pk;
#pragma unroll
    for (int d = 0; d < 4; ++d) {
      float v = Vtmp[(gl * 16 + q * 4 + d) * 16 + n];
      bf16_t hi = (bf16_t)v;
      pk.h[d] = hi;
      pk.h[4 + d] = (bf16_t)(v - (float)hi);
    }
    *(uint4*)(VF + ((size_t)(gbase + gl) * 64 + l) * 8) = pk.uu;
  }
}

// ================= attention partials =================
// Staging via async global_load_lds (16B/lane, no VGPR round-trip): F tile is a
// contiguous 32 KB copy (global layout == LDS image), VF tile 8 KB likewise.
// QK: mfma_16x16x32_bf16; F pre-scaled by sqrt(2*log2 e) -> w = exp2(cfr).
// PV: one MFMA per i-set, P truncated-bf16 packed via v_perm (bias cancels in
// the num/denom ratio), V interleaved {hi0..3, lo0..3} compensated split.
// LDS exactly 40960 B -> 4 blocks/CU; grid 1024 = 4 x 256 CUs, no tail.
__launch_bounds__(256, 4)
__global__ void kattn(const bf16_t* __restrict__ F, const bf16_t* __restrict__ VF,
                      float* __restrict__ P12) {
  __shared__ bf16_t Fs[BJ * 128];            // 32 KB, swizzled tile image
  __shared__ bf16_t Vs[(BJ / 16) * 512];     // 8 KB interleaved hi/lo frags
  int t = threadIdx.x;
  int lane = t & 63;
  int wave = t >> 6;    // 0..3
  int q = lane >> 4;    // 0..3
  int r = lane & 15;    // 0..15
  int i0 = blockIdx.x * BI + wave * 64;
  int jbase = blockIdx.y * JSEG;

  // stationary B-frags: 4 i-sets x 16 rows (from swizzled global layout)
  bf16x8 bfr[4][4];
#pragma unroll
  for (int s = 0; s < 4; ++s)
#pragma unroll
    for (int kk = 0; kk < 4; ++kk)
      bfr[s][kk] = *(const bf16x8*)(F + fidx(i0 + s * 16 + r, kk * 4 + q));

  f32x4 acc[4];
#pragma unroll
  for (int s = 0; s < 4; ++s) acc[s] = (f32x4){0.f, 0.f, 0.f, 0.f};

  for (int jt = 0; jt < JSEG; jt += BJ) {
    int j0 = jbase + jt;
    __syncthreads();
    // ---- async stage F tile (32 KB) + V tile (8 KB), 10 instrs/wave ----
    {
      const uint4* srcF = (const uint4*)(F + ((size_t)(j0 >> 7) << 14));
#pragma unroll
      for (int k = 0; k < 8; ++k) {
        int off = ((k * 4 + wave) << 6) + lane;   // 16B-chunk idx 0..2047
        __builtin_amdgcn_global_load_lds(
            (const __attribute__((address_space(1))) uint4*)(srcF + off),
            (__attribute__((address_space(3))) uint4*)((uint4*)Fs + off), 16, 0, 0);
      }
      const uint4* srcV = (const uint4*)(VF + ((size_t)(j0 >> 4) << 9));
#pragma unroll
      for (int k = 0; k < 2; ++k) {
        int off = ((k * 4 + wave) << 6) + lane;   // 0..511
        __builtin_amdgcn_global_load_lds(
            (const __attribute__((address_space(1))) uint4*)(srcV + off),
            (__attribute__((address_space(3))) uint4*)((uint4*)Vs + off), 16, 0, 0);
      }
    }
    __syncthreads();  // implicit vmcnt(0) drain: data resident

#pragma unroll
    for (int jj = 0; jj < BJ / 16; ++jj) {
      // A-frags for this 16-row j-chunk (shared across the 4 i-sets)
      bf16x8 afr[4];
      const bf16_t* fsrow = &Fs[(jj * 16 + r) * 128];
#pragma unroll
      for (int kk = 0; kk < 4; ++kk)
        afr[kk] = *(const bf16x8*)(fsrow + ((kk * 4 + q) ^ r) * 8);
      // V B-frag (hi at k-idx 0..3, lo at 4..7) for this j-chunk
      bf16x8 bv = *(const bf16x8*)&Vs[jj * 512 + lane * 8];
#pragma unroll
      for (int s = 0; s < 4; ++s) {
        f32x4 cfr = {0.f, 0.f, 0.f, 0.f};
#pragma unroll
        for (int kk = 0; kk < 4; ++kk)
          cfr = __builtin_amdgcn_mfma_f32_16x16x32_bf16(afr[kk], bfr[s][kk], cfr, 0, 0, 0);
        // w = exp(2*dot) = 2^cfr (scale folded into F); truncate-pack to bf16
        union { float f; u32 u; } w0, w1, w2, w3;
        w0.f = __builtin_amdgcn_exp2f(cfr[0]);
        w1.f = __builtin_amdgcn_exp2f(cfr[1]);
        w2.f = __builtin_amdgcn_exp2f(cfr[2]);
        w3.f = __builtin_amdgcn_exp2f(cfr[3]);
        union { u32 u[4]; bf16x8 v; } pf;
        pf.u[0] = __builtin_amdgcn_perm(w1.u, w0.u, 0x07060302u);  // {bf16(w0),bf16(w1)}
        pf.u[1] = __builtin_amdgcn_perm(w3.u, w2.u, 0x07060302u);
        pf.u[2] = pf.u[0];
        pf.u[3] = pf.u[1];
        acc[s] = __builtin_amdgcn_mfma_f32_16x16x32_bf16(pf.v, bv, acc[s], 0, 0, 0);
      }
    }
  }

  // acc[s] lane(q,r) reg rg = partial[row = i0+s*16+q*4+rg][col = r]
  if (r < 11) {
#pragma unroll
    for (int s = 0; s < 4; ++s) {
      float* op = P12 + (size_t)(i0 + s * 16 + q * 4) * VW + r;
      atomicAdd(&op[0 * VW], acc[s][0]);
      atomicAdd(&op[1 * VW], acc[s][1]);
      atomicAdd(&op[2 * VW], acc[s][2]);
      atomicAdd(&op[3 * VW], acc[s][3]);
    }
  }
}

// ---------------- finalize: class-count reduce + divides ----------------
__global__ void kfinal(float* __restrict__ out, const float* __restrict__ P12,
                       const float* __restrict__ clsPart) {
  __shared__ float clsS[16];
  int t = threadIdx.x;
  if (t < 64) {
    const float4* cp = (const float4*)clsPart;  // 64 rows x 4 float4
    float4 c0 = cp[t * 4], c1 = cp[t * 4 + 1], c2 = cp[t * 4 + 2], c3 = cp[t * 4 + 3];
#pragma unroll
    for (int off = 32; off >= 1; off >>= 1) {
      c0.x += __shfl_xor(c0.x, off); c0.y += __shfl_xor(c0.y, off);
      c0.z += __shfl_xor(c0.z, off); c0.w += __shfl_xor(c0.w, off);
      c1.x += __shfl_xor(c1.x, off); c1.y += __shfl_xor(c1.y, off);
      c1.z += __shfl_xor(c1.z, off); c1.w += __shfl_xor(c1.w, off);
      c2.x += __shfl_xor(c2.x, off); c2.y += __shfl_xor(c2.y, off);
    }
    if (t == 0) {
      *(float4*)&clsS[0] = c0;
      *(float4*)&clsS[4] = c1;
      clsS[8] = c2.x; clsS[9] = c2.y;
      clsS[10] = 0.f; clsS[11] = 0.f; clsS[12] = 0.f;
      clsS[13] = 0.f; clsS[14] = 0.f; clsS[15] = 0.f;
    }
  }
  __syncthreads();
  float d[NC]; float tot = 0.0f;
#pragma unroll
  for (int c = 0; c < NC; ++c) { d[c] = clsS[c]; tot += d[c]; }
  int row = blockIdx.x * 256 + t;  // 64 blocks x 256
  const float* pr = P12 + (size_t)row * VW;
  float rs = 1.0f / pr[10];
  float* op = out + (size_t)row * NC;
#pragma unroll
  for (int c = 0; c < NC; ++c) {
    float den = (d[c] == 0.0f) ? tot : d[c];
    op[c] = pr[c] * rs / den;
  }
}

extern "C" void kernel_launch(void* const* d_in, const int* in_sizes, int n_in,
                              void* d_out, int out_size, void* d_ws, size_t ws_size,
                              hipStream_t stream) {
  const float* anchor   = (const float*)d_in[0];  // 6144x128
  const float* positive = (const float*)d_in[1];  // 6144x128
  const float* lbfeat   = (const float*)d_in[2];  // 4096x128
  const float* onehot   = (const float*)d_in[3];  // 4096x10
  const float* l1       = (const float*)d_in[4];  // 6144x10
  const float* l2       = (const float*)d_in[5];  // 6144x10
  float* out = (float*)d_out;                     // 16384x10

  char* ws = (char*)d_ws;
  bf16_t* F       = (bf16_t*)ws;                               // 4 MiB (swizzled tiles)
  bf16_t* VF      = (bf16_t*)(ws + 4194304);                   // 1 MiB (frag layout)
  float*  P12     = (float*)(ws + 4194304 + 1048576);          // 768 KiB
  float*  clsPart = (float*)(ws + 4194304 + 1048576 + 786432); // 64x16 floats = 4 KiB

  kprep2<<<1088, 256, 0, stream>>>(lbfeat, anchor, positive, onehot, l1, l2,
                                   F, VF, clsPart, P12);
  kattn<<<dim3(NROWS / BI, SEG), 256, 0, stream>>>(F, VF, P12);
  kfinal<<<NROWS / 256, 256, 0, stream>>>(out, P12, clsPart);
}